// Round 3
// baseline (1816.584 us; speedup 1.0000x reference)
//
#include <hip/hip_runtime.h>

#define BB 8
#define TT 2048
#define CC 1024
#define FF 4096
#define MM (BB*TT)   // 16384

typedef unsigned short u16;
typedef __bf16 bf16x8 __attribute__((ext_vector_type(8)));
typedef float f32x4 __attribute__((ext_vector_type(4)));

__device__ __forceinline__ u16 f2bf(float f) {
  unsigned int u = __float_as_uint(f);
  u += 0x7fffu + ((u >> 16) & 1u);     // RNE to bf16
  return (u16)(u >> 16);
}
__device__ __forceinline__ float bf2f(u16 h) {
  unsigned int u = ((unsigned int)h) << 16;
  return __uint_as_float(u);
}
__device__ __forceinline__ float sigm(float x) { return 1.f / (1.f + __expf(-x)); }

__device__ __forceinline__ void async16(const void* g, void* l) {
  __builtin_amdgcn_global_load_lds(
      (const __attribute__((address_space(1))) unsigned int*)g,
      (__attribute__((address_space(3))) unsigned int*)l, 16, 0, 0);
}

// ---------------------------------------------------------------------------
// NT GEMM: C[m,n] = sum_k A[m,k]*W[n,k], A [M,K] bf16 row-major, W [N,K] bf16.
//
// 256x256 tile, BK=64, 512 thr (8 waves 2Mx4N; per wave 128x64 out = 8x4
// frags of 16x16x32 MFMA). Pipelined 4-phase K-tile schedule:
//   - fragments ds_read ONE PHASE AHEAD into the idle register bank, so each
//     phase's MFMA burst starts with zero waits (round-1 diagnosis: same-phase
//     read->use exposed the whole LDS queue+latency serially before MFMA)
//   - phase = {reads(next) [+ staging Q2/Q3] -> sched_barrier -> setprio(1)
//     16 MFMA setprio(0) -> lgkmcnt(0) -> [vmcnt(0) @Q1 only] -> ONE barrier}
//   - reads:  Q0:a1(t)  Q1:b23(t)  Q2:b01(t+1)  Q3:a0(t+1)
//   - stages (ALL in Q2/Q3, tile t+2 into buf BETA(t); every concurrent
//     ds_read targets buf BETA^1, so no read/write buffer overlap):
//       Q2: A(t+2) r0,r1 + B(t+2) q0,q1   (regions dead since Q0/Q1/prev)
//       Q3: A(t+2) r2,r3 + B(t+2) q2,q3
//     single unconditional vmcnt(0) at every tile's Q1-end gates ALL staging
//     (issue->gate = 2-3 phases ~1200-1800cy >= HBM latency; reads of staged
//     data occur only at >= t+1.Q2, strictly after the gate+barrier).
//     Overwrite safety: each region's last ds_read is drained by that phase's
//     lgkmcnt(0) + barrier before the staging phase issues.
//   - B LDS layout permuted to [half(32r)][band(wni)][32 rows] so b01/b23 are
//     contiguous halves aligned with 64-row staging rounds
//   - chunk^row&7 source-side XOR swizzle: every consecutive-8-lane group of
//     a ds_read_b128 covers all 32 banks exactly once (conflict-free)
//   - 2 K-tiles unrolled/iter -> all LDS offsets are `offset:` immediates
// MODE 0: Cf[idx] = v (f32).      MODE 2: Cb[idx] = bf16(relu(v)^2).
// MODE 3: Cb[idx] = bf16(v).      MODE 4: Cf[idx] += sigm(R[idx]) * v.
// ---------------------------------------------------------------------------
#define GROUP_M 16

#define DSRD(d, a, o) \
  asm volatile("ds_read_b128 %0, %1 offset:%c2" : "=v"(d) : "v"(a), "i"(o))

#define MFMA16(A_, B_, C_) \
  (C_) = __builtin_amdgcn_mfma_f32_16x16x32_bf16( \
      __builtin_bit_cast(bf16x8, (A_)), __builtin_bit_cast(bf16x8, (B_)), (C_), 0, 0, 0)

// 8 ds_read_b128: A fragment rows (wmi*128 + (MB+mi)*16 + lm), kh=0,1
#define READ_A(bank, BETA, MB) do { \
  DSRD(bank[0][0], aAddr0, (BETA)*32768 + ((MB)+0)*2048); \
  DSRD(bank[0][1], aAddr1, (BETA)*32768 + ((MB)+0)*2048); \
  DSRD(bank[1][0], aAddr0, (BETA)*32768 + ((MB)+1)*2048); \
  DSRD(bank[1][1], aAddr1, (BETA)*32768 + ((MB)+1)*2048); \
  DSRD(bank[2][0], aAddr0, (BETA)*32768 + ((MB)+2)*2048); \
  DSRD(bank[2][1], aAddr1, (BETA)*32768 + ((MB)+2)*2048); \
  DSRD(bank[3][0], aAddr0, (BETA)*32768 + ((MB)+3)*2048); \
  DSRD(bank[3][1], aAddr1, (BETA)*32768 + ((MB)+3)*2048); \
} while (0)

// 4 ds_read_b128: B fragment rows, permuted layout rho=(ni>>1)*128+wni*32+(ni&1)*16+lm
#define READ_B(bank, BETA, NB) do { \
  DSRD(bank[0][0], bAddr0, (BETA)*32768 + (((NB)+0)>>1)*16384 + (((NB)+0)&1)*2048); \
  DSRD(bank[0][1], bAddr1, (BETA)*32768 + (((NB)+0)>>1)*16384 + (((NB)+0)&1)*2048); \
  DSRD(bank[1][0], bAddr0, (BETA)*32768 + (((NB)+1)>>1)*16384 + (((NB)+1)&1)*2048); \
  DSRD(bank[1][1], bAddr1, (BETA)*32768 + (((NB)+1)>>1)*16384 + (((NB)+1)&1)*2048); \
} while (0)

#define QMFMA(ABANK, BBANK, AO, NO) do { \
  _Pragma("unroll") \
  for (int mi = 0; mi < 4; ++mi) \
    _Pragma("unroll") \
    for (int ni = 0; ni < 2; ++ni) { \
      MFMA16(ABANK[mi][0], BBANK[ni][0], acc[(AO)+mi][(NO)+ni]); \
      MFMA16(ABANK[mi][1], BBANK[ni][1], acc[(AO)+mi][(NO)+ni]); \
    } \
} while (0)

#define PH_EXEC_BEGIN() do { \
  __builtin_amdgcn_sched_barrier(0); \
  __builtin_amdgcn_s_setprio(1); } while (0)

#define PH_EXEC_END(GATE) do { \
  __builtin_amdgcn_s_setprio(0); \
  __builtin_amdgcn_sched_barrier(0); \
  asm volatile("s_waitcnt lgkmcnt(0)"); \
  if (GATE) asm volatile("s_waitcnt vmcnt(0)"); \
  __builtin_amdgcn_s_barrier(); \
  __builtin_amdgcn_sched_barrier(0); } while (0)

// one K-tile: 4 phases. T2A = t+2 (staging target tile). Flags compile-time.
#define TILE(T2A, BETA, DOSTAGE, RDQ2, RDQ3) do { \
  /* Q0: MFMA a0 x b01 ; read a1(t) */ \
  READ_A(a1, BETA, 4); \
  PH_EXEC_BEGIN(); QMFMA(a0, b01, 0, 0); PH_EXEC_END(0); \
  /* Q1: MFMA a1 x b01 ; read b23(t) ; vmcnt(0) gate for ALL staging */ \
  READ_B(b23, BETA, 2); \
  PH_EXEC_BEGIN(); QMFMA(a1, b01, 4, 0); PH_EXEC_END(1); \
  /* Q2: MFMA a0 x b23 ; read b01(t+1) ; stage A(t+2) r0,r1 + B(t+2) q0,q1 */ \
  if (RDQ2) READ_B(b01, (BETA)^1, 0); \
  if (DOSTAGE) { stA(BETA, 0, T2A); stA(BETA, 1, T2A); \
                 stB(BETA, 0, T2A); stB(BETA, 1, T2A); } \
  PH_EXEC_BEGIN(); QMFMA(a0, b23, 0, 2); PH_EXEC_END(0); \
  /* Q3: MFMA a1 x b23 ; read a0(t+1) ; stage A(t+2) r2,r3 + B(t+2) q2,q3 */ \
  if (RDQ3) READ_A(a0, (BETA)^1, 0); \
  if (DOSTAGE) { stA(BETA, 2, T2A); stA(BETA, 3, T2A); \
                 stB(BETA, 2, T2A); stB(BETA, 3, T2A); } \
  PH_EXEC_BEGIN(); QMFMA(a1, b23, 4, 2); PH_EXEC_END(0); \
} while (0)

template<int MODE>
__global__ __launch_bounds__(512, 2) void gemm_bt(
    const u16* __restrict__ A, const u16* __restrict__ W,
    float* __restrict__ Cf, u16* __restrict__ Cb,
    const u16* __restrict__ R, int N, int K)
{
  __shared__ __align__(16) u16 ldsA[2][256 * 64];   // 64 KB
  __shared__ __align__(16) u16 ldsB[2][256 * 64];   // 64 KB (permuted layout)

  const int tid  = threadIdx.x;
  const int wave = tid >> 6;
  const int lane = tid & 63;
  const int wmi  = wave >> 2;          // 0..1 : wave M row (128 rows each)
  const int wni  = wave & 3;           // 0..3 : wave N col (64 cols each)
  const int lm   = lane & 15;
  const int lq   = lane >> 4;

  // tile swizzle (grid.x = M/256, divisible by GROUP_M; grid.y = N-tiles)
  const int bid  = blockIdx.x + blockIdx.y * gridDim.x;
  const int gsz  = GROUP_M * gridDim.y;
  const int gid  = bid / gsz;
  const int rem  = bid - gid * gsz;
  const int bm   = (gid * GROUP_M + (rem % GROUP_M)) * 256;
  const int bn   = (rem / GROUP_M) * 256;

  const int NT = K >> 6;               // K-tiles of 64 (NT even, >= 4)

  // staging: round q = 64 LDS rows; wave w writes rows q*64+w*8 .. +8.
  // source chunk pre-swizzle: LDS chunk (lane&7) <- global chunk (lane&7)^(lane>>3)
  const int ls     = lane >> 3;
  const int schunk = (lane & 7) ^ ls;
  const int rowA   = wave * 8 + ls;                              // A: rho == global row
  const int rowB   = (wave >> 2) * 64 + (wave & 3) * 8 + ls;     // B: base of permuted map
  const u16* gA = A + (size_t)(bm + rowA) * K + schunk * 8;
  const u16* gB = W + (size_t)(bn + rowB) * K + schunk * 8;
  const size_t rowK = (size_t)64 * K;

  auto stA = [&](int buf, int q, int t2) {
    async16(gA + (size_t)t2 * 64 + (size_t)q * rowK,
            &ldsA[buf][(q * 64 + wave * 8) * 64]);
  };
  // B permuted: LDS rho = half*128 + band*32 + r ; global row = band*64+half*32+r
  // => per-q global row delta from rowB: {0,128,32,160}
  auto stB = [&](int buf, int q, int t2) {
    const int qrow = (q == 0) ? 0 : (q == 1) ? 128 : (q == 2) ? 32 : 160;
    async16(gB + (size_t)t2 * 64 + (size_t)qrow * K,
            &ldsB[buf][(q * 64 + wave * 8) * 64]);
  };

  const unsigned lAbase =
      (unsigned)(size_t)(const __attribute__((address_space(3))) u16*)&ldsA[0][0];
  const unsigned lBbase =
      (unsigned)(size_t)(const __attribute__((address_space(3))) u16*)&ldsB[0][0];
  // A frag: row = wmi*128 + mi*16 + lm, byte = row*128 + ((lq+4kh)^(lm&7))*16
  const unsigned aAddr0 = lAbase + (unsigned)((wmi * 128 + lm) * 128 + (((lq    ) ^ (lm & 7)) * 16));
  const unsigned aAddr1 = lAbase + (unsigned)((wmi * 128 + lm) * 128 + (((lq + 4) ^ (lm & 7)) * 16));
  // B frag: rho = (ni>>1)*128 + wni*32 + (ni&1)*16 + lm  (ni via offset imm)
  const unsigned bAddr0 = lBbase + (unsigned)((wni * 32 + lm) * 128 + (((lq    ) ^ (lm & 7)) * 16));
  const unsigned bAddr1 = lBbase + (unsigned)((wni * 32 + lm) * 128 + (((lq + 4) ^ (lm & 7)) * 16));

  f32x4 acc[8][4] = {};
  f32x4 a0[4][2], a1[4][2], b01[2][2], b23[2][2];   // static-indexed banks

  // ---------------- prologue: stage tiles 0,1 fully; preload a0(0), b01(0)
  stA(0, 0, 0); stA(0, 1, 0); stA(0, 2, 0); stA(0, 3, 0);
  stB(0, 0, 0); stB(0, 1, 0); stB(0, 2, 0); stB(0, 3, 0);
  stA(1, 0, 1); stA(1, 1, 1); stA(1, 2, 1); stA(1, 3, 1);
  stB(1, 0, 1); stB(1, 1, 1); stB(1, 2, 1); stB(1, 3, 1);
  asm volatile("s_waitcnt vmcnt(0)");
  __builtin_amdgcn_s_barrier();
  READ_A(a0, 0, 0);
  READ_B(b01, 0, 0);
  asm volatile("s_waitcnt lgkmcnt(0)");
  __builtin_amdgcn_sched_barrier(0);
  __builtin_amdgcn_s_barrier();

  // ---------------- main loop: tiles 0 .. NT-3 (2 per iter)
  for (int t = 0; t + 3 < NT; t += 2) {
    TILE(t + 2, 0, 1, 1, 1);
    TILE(t + 3, 1, 1, 1, 1);
  }

  // ---------------- tail: tiles NT-2 (buf0), NT-1 (buf1); no staging.
  // The Q1 vmcnt(0) gate inside TILE drains the last staging before use.
  TILE(0, 0, 0, 1, 1);
  TILE(0, 1, 0, 0, 0);

  // epilogue. C/D layout (verified m89/m91): col = lane&15, row = (lane>>4)*4 + reg
  const int row0 = bm + wmi * 128 + lq * 4;
  const int col0 = bn + wni * 64 + lm;
#pragma unroll
  for (int mi = 0; mi < 8; ++mi)
#pragma unroll
    for (int ni = 0; ni < 4; ++ni) {
      size_t base = (size_t)(row0 + mi * 16) * N + (col0 + ni * 16);
#pragma unroll
      for (int r2 = 0; r2 < 4; ++r2) {
        size_t idx = base + (size_t)r2 * N;
        float v = acc[mi][ni][r2];
        if (MODE == 0) Cf[idx] = v;
        if (MODE == 2) { float rl = v > 0.f ? v : 0.f; Cb[idx] = f2bf(rl * rl); }
        if (MODE == 3) Cb[idx] = f2bf(v);
        if (MODE == 4) Cf[idx] += sigm(bf2f(R[idx])) * v;
      }
    }
}

// ---------------------------------------------------------------------------
// LayerNorm both rows t and t-1, time-shift mix, bf16 cast.
// One block per row (b,t). ov/oxb may be null (phase-2 use).
// oxb (raw x cast) is written at pitch 2*CC (the A' interleaved buffer).
// ---------------------------------------------------------------------------
__global__ __launch_bounds__(256) void prep_mix(
    const float* __restrict__ x,
    const float* __restrict__ lnw, const float* __restrict__ lnb,
    const float* __restrict__ mk, const float* __restrict__ mv, const float* __restrict__ mr,
    u16* __restrict__ ok, u16* __restrict__ ov, u16* __restrict__ orr,
    u16* __restrict__ oxb)
{
  const int m = blockIdx.x;
  const int t = m & (TT - 1);
  const int tid = threadIdx.x;
  const int wave = tid >> 6, lane = tid & 63;
  const bool hasp = (t != 0);

  const float4 xc4 = ((const float4*)(x + (size_t)m * CC))[tid];
  float4 xp4 = make_float4(0.f, 0.f, 0.f, 0.f);
  if (hasp) xp4 = ((const float4*)(x + (size_t)(m - 1) * CC))[tid];

  float s0 = xc4.x + xc4.y + xc4.z + xc4.w;
  float s1 = xc4.x*xc4.x + xc4.y*xc4.y + xc4.z*xc4.z + xc4.w*xc4.w;
  float s2 = xp4.x + xp4.y + xp4.z + xp4.w;
  float s3 = xp4.x*xp4.x + xp4.y*xp4.y + xp4.z*xp4.z + xp4.w*xp4.w;
#pragma unroll
  for (int off2 = 32; off2 > 0; off2 >>= 1) {
    s0 += __shfl_xor(s0, off2);
    s1 += __shfl_xor(s1, off2);
    s2 += __shfl_xor(s2, off2);
    s3 += __shfl_xor(s3, off2);
  }
  __shared__ float red[4][4];
  if (lane == 0) { red[0][wave] = s0; red[1][wave] = s1; red[2][wave] = s2; red[3][wave] = s3; }
  __syncthreads();
  const float S0 = red[0][0] + red[0][1] + red[0][2] + red[0][3];
  const float S1 = red[1][0] + red[1][1] + red[1][2] + red[1][3];
  const float S2 = red[2][0] + red[2][1] + red[2][2] + red[2][3];
  const float S3 = red[3][0] + red[3][1] + red[3][2] + red[3][3];
  const float inv = 1.f / (float)CC;
  const float muc = S0 * inv, varc = S1 * inv - muc * muc, rsc = rsqrtf(varc + 1e-5f);
  const float mup = S2 * inv, varp = S3 * inv - mup * mup, rsp = rsqrtf(varp + 1e-5f);

  const float xc[4] = {xc4.x, xc4.y, xc4.z, xc4.w};
  const float xp[4] = {xp4.x, xp4.y, xp4.z, xp4.w};
  const float4 lw4 = ((const float4*)lnw)[tid];
  const float4 lb4 = ((const float4*)lnb)[tid];
  const float lw[4] = {lw4.x, lw4.y, lw4.z, lw4.w};
  const float lb[4] = {lb4.x, lb4.y, lb4.z, lb4.w};
  const float4 mk4 = ((const float4*)mk)[tid];
  const float mka[4] = {mk4.x, mk4.y, mk4.z, mk4.w};
  const float4 mr4 = ((const float4*)mr)[tid];
  const float mra[4] = {mr4.x, mr4.y, mr4.z, mr4.w};
  float mva[4] = {0.f, 0.f, 0.f, 0.f};
  if (ov) {
    const float4 mv4 = ((const float4*)mv)[tid];
    mva[0] = mv4.x; mva[1] = mv4.y; mva[2] = mv4.z; mva[3] = mv4.w;
  }

  ushort4 wk2, wv2, wr2, wb2;
  u16* pk = (u16*)&wk2; u16* pv = (u16*)&wv2; u16* pr = (u16*)&wr2; u16* pb = (u16*)&wb2;
#pragma unroll
  for (int j = 0; j < 4; ++j) {
    float h  = (xc[j] - muc) * rsc * lw[j] + lb[j];
    float hh = hasp ? (xp[j] - mup) * rsp * lw[j] + lb[j] : 0.f;
    pk[j] = f2bf(h * mka[j] + hh * (1.f - mka[j]));
    pv[j] = f2bf(h * mva[j] + hh * (1.f - mva[j]));
    pr[j] = f2bf(h * mra[j] + hh * (1.f - mra[j]));
    pb[j] = f2bf(xc[j]);
  }
  ((ushort4*)(ok + (size_t)m * CC))[tid] = wk2;
  if (ov)  ((ushort4*)(ov  + (size_t)m * CC))[tid] = wv2;
  ((ushort4*)(orr + (size_t)m * CC))[tid] = wr2;
  if (oxb) ((ushort4*)(oxb + (size_t)m * (2 * CC)))[tid] = wb2;   // A' xb half
}

// ---------------------------------------------------------------------------
// WKV blocked 3-phase parallel scan. Output goes to the rwkv half of the
// interleaved A' buffer: out pitch = 2*CC.
// ---------------------------------------------------------------------------
#define WKV_CPB 32
#define WKV_NCH 32
#define WKV_L   (TT / WKV_NCH)   // 64

__global__ __launch_bounds__(1024) void wkv_scan(
    const u16* __restrict__ k, const u16* __restrict__ v, const u16* __restrict__ r,
    const float* __restrict__ decay, const float* __restrict__ first,
    u16* __restrict__ out)   // points at A' + CC (rwkv half), pitch 2*CC
{
  const int b  = blockIdx.x >> 5;
  const int c0 = (blockIdx.x & 31) * WKV_CPB;
  const int tid = threadIdx.x;
  const int cl = tid & 31;
  const int j  = tid >> 5;
  const int c  = c0 + cl;

  const float w   = -__expf(decay[c]);
  const float lam = __expf(w);
  const float eu  = __expf(first[c]);

  const size_t base  = (size_t)b * TT * CC + (size_t)j * WKV_L * CC + c;
  size_t obase = ((size_t)b * TT + (size_t)j * WKV_L) * (2 * CC) + c;

  // phase 1: local scan (state only)
  float a = 0.f, bb = 0.f;
  size_t idx = base;
  for (int i = 0; i < WKV_L; ++i, idx += CC) {
    const float kt = bf2f(k[idx]), vt = bf2f(v[idx]);
    const float ek = __expf(kt);
    a  = fmaf(lam, a, ek * vt);
    bb = fmaf(lam, bb, ek);
  }

  // phase 2: exclusive carry scan over chunks
  __shared__ float sA[WKV_NCH][WKV_CPB];
  __shared__ float sB[WKV_NCH][WKV_CPB];
  sA[j][cl] = a; sB[j][cl] = bb;
  __syncthreads();
  if (tid < WKV_CPB) {
    float ca = 0.f, cb = 0.f;
    const float cw   = -__expf(decay[c0 + tid]);
    const float cLam = __expf(cw * (float)WKV_L);
#pragma unroll
    for (int q = 0; q < WKV_NCH; ++q) {
      const float ta = sA[q][tid], tb = sB[q][tid];
      sA[q][tid] = ca; sB[q][tid] = cb;
      ca = fmaf(cLam, ca, ta);
      cb = fmaf(cLam, cb, tb);
    }
  }
  __syncthreads();
  a = sA[j][cl]; bb = sB[j][cl];

  // phase 3: replay with carry-in, emit sigmoid(r)*y into A' rwkv half
  idx = base;
  for (int i = 0; i < WKV_L; ++i, idx += CC, obase += 2 * CC) {
    const float kt = bf2f(k[idx]), vt = bf2f(v[idx]), rt = bf2f(r[idx]);
    const float ek = __expf(kt);
    const float e2 = eu * ek;
    const float y  = (a + e2 * vt) / (bb + e2);
    out[obase] = f2bf(sigm(rt) * y);
    a  = fmaf(lam, a, ek * vt);
    bb = fmaf(lam, bb, ek);
  }
}

// ---------------------------------------------------------------------------
// Weight f32 -> bf16 conversion. Segments 3 (Wo) and 4 (Wsh) are interleaved
// into W' = [Wsh | Wo] rows of pitch 2048 for the merged short+Wo GEMM.
// ---------------------------------------------------------------------------
struct ConvArgs { const float* src[8]; int end[8]; int dstoff[8]; };

__global__ __launch_bounds__(256) void conv_w(ConvArgs args, u16* __restrict__ dst)
{
  const int i = (blockIdx.x * 256 + threadIdx.x) * 4;
  int seg = 0;
  const float* sp = args.src[0];
  int base = 0;
#pragma unroll
  for (int s = 1; s < 8; ++s) {
    if (i >= args.end[s - 1]) { seg = s; sp = args.src[s]; base = args.end[s - 1]; }
  }
  const int l = i - base;
  const float4 vv = *(const float4*)(sp + l);
  int dsti;
  if (seg == 3)      { int row = l >> 10, col = l & 1023; dsti = args.dstoff[3] + row * 2048 + 1024 + col; }
  else if (seg == 4) { int row = l >> 10, col = l & 1023; dsti = args.dstoff[4] + row * 2048 + col; }
  else               dsti = args.dstoff[seg] + l;
  ushort4 d;
  d.x = f2bf(vv.x); d.y = f2bf(vv.y); d.z = f2bf(vv.z); d.w = f2bf(vv.w);
  *(ushort4*)(dst + dsti) = d;
}

extern "C" void kernel_launch(void* const* d_in, const int* in_sizes, int n_in,
                              void* d_out, int out_size, void* d_ws, size_t ws_size,
                              hipStream_t stream)
{
  const float* x    = (const float*)d_in[0];
  const float* ln1w = (const float*)d_in[1];
  const float* ln1b = (const float*)d_in[2];
  const float* ln2w = (const float*)d_in[3];
  const float* ln2b = (const float*)d_in[4];
  const float* tdec = (const float*)d_in[5];
  const float* tfir = (const float*)d_in[6];
  const float* amk  = (const float*)d_in[7];
  const float* amv  = (const float*)d_in[8];
  const float* amr  = (const float*)d_in[9];
  const float* Wk   = (const float*)d_in[10];
  const float* Wv   = (const float*)d_in[11];
  const float* Wr   = (const float*)d_in[12];
  const float* Wo   = (const float*)d_in[13];
  const float* fmk  = (const float*)d_in[14];
  const float* fmr  = (const float*)d_in[15];
  const float* WfK  = (const float*)d_in[16];
  const float* WfR  = (const float*)d_in[17];
  const float* WfV  = (const float*)d_in[18];
  const float* Wsh  = (const float*)d_in[19];
  float* out = (float*)d_out;
  char* ws = (char*)d_ws;

  // workspace: 28 MB bf16 weights + six 32 MB regions = 230,686,720 B total.
  u16* wW = (u16*)(ws);
  u16* U0 = (u16*)(ws + 29360128);
  u16* U1 = (u16*)(ws + 62914560);
  u16* U2 = (u16*)(ws + 96468992);
  u16* U3 = (u16*)(ws + 130023424);
  u16* U4 = (u16*)(ws + 163577856);   // A' = U4+U5, 64 MB contiguous

  // liveness-based aliases:
  u16* xk   = U0;          // prep1
  u16* xv   = U1;
  u16* xr   = U2;
  u16* Ap   = U4;          // A' [M, 2C]: cols 0..C-1 = bf16(x), C..2C-1 = rwkv
  u16* kbuf = U3;          // k = xk*Wk   (U0 dead after)
  u16* vbuf = U0;          // v = xv*Wv   (U1 dead after)
  u16* rbuf = U1;          // r = xr*Wr   (U2 dead after)
  u16* gk   = U0;          // prep2       (U0 dead after wkv)
  u16* gr   = U1;
  u16* kkb  = U2;          // kk [M,F] bf16 = 128 MB, spans U2..U5 (all dead)
  u16* rffn = U0;          // r_ffn       (gk/U0 dead after kk GEMM)

  u16* bWk   = wW + 0;
  u16* bWv   = wW + 1048576;
  u16* bWr   = wW + 2097152;
  u16* bWsWo = wW + 3145728;   // W' [C, 2C] interleaved [Wsh | Wo]
  u16* bWfR  = wW + 5242880;
  u16* bWfK  = wW + 6291456;
  u16* bWfV  = wW + 10485760;

  ConvArgs ca;
  ca.src[0] = Wk;  ca.src[1] = Wv;  ca.src[2] = Wr;  ca.src[3] = Wo;
  ca.src[4] = Wsh; ca.src[5] = WfR; ca.src[6] = WfK; ca.src[7] = WfV;
  const int e = 1048576;
  ca.end[0] = e;     ca.end[1] = 2*e;  ca.end[2] = 3*e;  ca.end[3] = 4*e;
  ca.end[4] = 5*e;   ca.end[5] = 6*e;  ca.end[6] = 10*e; ca.end[7] = 14*e;
  ca.dstoff[0] = 0;     ca.dstoff[1] = e;    ca.dstoff[2] = 2*e;
  ca.dstoff[3] = 3*e;   ca.dstoff[4] = 3*e;  // both into W' (interleaved)
  ca.dstoff[5] = 5*e;   ca.dstoff[6] = 6*e;  ca.dstoff[7] = 10*e;

  conv_w<<<14336, 256, 0, stream>>>(ca, wW);
  prep_mix<<<MM, 256, 0, stream>>>(x, ln1w, ln1b, amk, amv, amr, xk, xv, xr, Ap);

  dim3 g8(MM / 256, CC / 256);
  gemm_bt<3><<<g8, 512, 0, stream>>>(xk, bWk, nullptr, kbuf, nullptr, CC, CC);
  gemm_bt<3><<<g8, 512, 0, stream>>>(xv, bWv, nullptr, vbuf, nullptr, CC, CC);
  gemm_bt<3><<<g8, 512, 0, stream>>>(xr, bWr, nullptr, rbuf, nullptr, CC, CC);

  wkv_scan<<<BB * (CC / WKV_CPB), 1024, 0, stream>>>(kbuf, vbuf, rbuf, tdec, tfir, Ap + CC);

  // out = [xb | rwkv] * [Wsh | Wo]^T   (single K=2048 GEMM)
  gemm_bt<0><<<g8, 512, 0, stream>>>(Ap, bWsWo, out, nullptr, nullptr, CC, 2 * CC);

  prep_mix<<<MM, 256, 0, stream>>>(out, ln2w, ln2b, fmk, nullptr, fmr, gk, nullptr, gr, nullptr);

  dim3 gF(MM / 256, FF / 256);
  gemm_bt<2><<<gF, 512, 0, stream>>>(gk, bWfK, nullptr, kkb, nullptr, FF, CC);  // kk = relu(gk*WfK)^2
  gemm_bt<3><<<g8, 512, 0, stream>>>(gr, bWfR, nullptr, rffn, nullptr, CC, CC);
  // out += sigm(rffn) * (kk * WfV)   (fused final_add)
  gemm_bt<4><<<g8, 512, 0, stream>>>(kkb, bWfV, out, nullptr, rffn, CC, FF);
}

// Round 4
// 925.833 us; speedup vs baseline: 1.9621x; 1.9621x over previous
//
#include <hip/hip_runtime.h>

#define BB 8
#define TT 2048
#define CC 1024
#define FF 4096
#define MM (BB*TT)   // 16384

typedef unsigned short u16;
typedef __bf16 bf16x8 __attribute__((ext_vector_type(8)));
typedef float f32x4 __attribute__((ext_vector_type(4)));

__device__ __forceinline__ u16 f2bf(float f) {
  unsigned int u = __float_as_uint(f);
  u += 0x7fffu + ((u >> 16) & 1u);     // RNE to bf16
  return (u16)(u >> 16);
}
__device__ __forceinline__ float bf2f(u16 h) {
  unsigned int u = ((unsigned int)h) << 16;
  return __uint_as_float(u);
}
__device__ __forceinline__ float sigm(float x) { return 1.f / (1.f + __expf(-x)); }

__device__ __forceinline__ void async16(const void* g, void* l) {
  __builtin_amdgcn_global_load_lds(
      (const __attribute__((address_space(1))) unsigned int*)g,
      (__attribute__((address_space(3))) unsigned int*)l, 16, 0, 0);
}

// ---------------------------------------------------------------------------
// NT GEMM: C[m,n] = sum_k A[m,k]*W[n,k], A [M,K] bf16 row-major, W [N,K] bf16.
//
// 256x256 tile, BK=64, 512 thr (8 waves 2Mx4N; per wave 128x64 out = 8x4
// frags of 16x16x32 MFMA). 8-phase K-tile schedule, 8 MFMA/phase, with
// fragment banks sized to fit the 256-reg/wave budget (round-3 lesson:
// 4 full banks = 96 frag regs spilled; these banks peak at 64):
//   aX/aY/aZ: 4 frags (one M-half, one kh) = 16 regs each
//   bP/bQ   : 2 frags (one N-pair,  one kh) =  8 regs each
// Phase uses (Euler order -> every bank's uses adjacent):
//   P0: aX(M0k0) x bP(N01k0)   P4: aZ(M0k1) x bP(N01k1)
//   P1: aY(M1k0) x bP          P5: aY(M1k1) x bP
//   P2: aY       x bQ(N23k0)   P6: aY       x bQ(N23k1)
//   P3: aX       x bQ          P7: aZ       x bQ
// Reads (>=1 phase ahead of first use; counted lgkm gate before MFMA waits
// only for *older* reads, leaving this+future-phase reads in flight):
//   P0: bQ<-B1k0[2]  P1: aZ<-A0k1[4]  P2: bP<-B0k1[2]  P3: --
//   P4: aY<-A1k1[4]  P5: bQ<-B1k1[2]  P6: aX<-A0k0'[4]+bP<-B0k0'[2]
//   P7: aY<-A1k0'[4]      gates: 2,6,6,6,4,2,6,10
// Staging (tile t+2 into buf[t&1], 2 glds/phase P4..P7; region last-reads:
// A-q0/q1@P1, A-q2/q3@P4, B-q0/q1@P2, B-q2/q3@P5 -> all dead >=1 barrier
// before overwrite). Rolling vmcnt(4) at P5 (steady: leaves P4,P5's 4 in
// flight, drains tile-(t+1) stages issued P4-P7(t-1); first read of that
// data is P6(t) - after the gate). Tail tiles: vmcnt(0), 6-phase distance.
// B LDS layout permuted [half][band][32rows]; chunk^row&7 source-side XOR
// swizzle (conflict-free, validated round 1/3); layout identical to round 3
// which passed correctness.
// MODE 0: Cf[idx] = v (f32).      MODE 2: Cb[idx] = bf16(relu(v)^2).
// MODE 3: Cb[idx] = bf16(v).      MODE 4: Cf[idx] += sigm(R[idx]) * v.
// ---------------------------------------------------------------------------
#define GROUP_M 16

#define DSRD(d, a, o) \
  asm volatile("ds_read_b128 %0, %1 offset:%c2" : "=v"(d) : "v"(a), "i"(o))

#define MFMA16(A_, B_, C_) \
  (C_) = __builtin_amdgcn_mfma_f32_16x16x32_bf16( \
      __builtin_bit_cast(bf16x8, (A_)), __builtin_bit_cast(bf16x8, (B_)), (C_), 0, 0, 0)

#define SCHED0  __builtin_amdgcn_sched_barrier(0)
#define BARRIER __builtin_amdgcn_s_barrier()
#define LGKM(n) asm volatile("s_waitcnt lgkmcnt(" #n ")")

#define READ_A4(bank, BETA, MH, KH) do { \
  DSRD(bank[0], aAddr##KH, (BETA)*32768 + ((MH)*4+0)*2048); \
  DSRD(bank[1], aAddr##KH, (BETA)*32768 + ((MH)*4+1)*2048); \
  DSRD(bank[2], aAddr##KH, (BETA)*32768 + ((MH)*4+2)*2048); \
  DSRD(bank[3], aAddr##KH, (BETA)*32768 + ((MH)*4+3)*2048); \
} while (0)

#define READ_B2(bank, BETA, NP, KH) do { \
  DSRD(bank[0], bAddr##KH, (BETA)*32768 + (NP)*16384 + 0*2048); \
  DSRD(bank[1], bAddr##KH, (BETA)*32768 + (NP)*16384 + 1*2048); \
} while (0)

#define MFMA8(ABANK, BBANK, AO, NO) do { \
  _Pragma("unroll") \
  for (int mi = 0; mi < 4; ++mi) \
    _Pragma("unroll") \
    for (int ni = 0; ni < 2; ++ni) \
      MFMA16(ABANK[mi], BBANK[ni], acc[(AO)+mi][(NO)+ni]); \
} while (0)

#define EXEC8(ABANK, BBANK, AO, NO) do { \
  SCHED0; __builtin_amdgcn_s_setprio(1); \
  MFMA8(ABANK, BBANK, AO, NO); \
  __builtin_amdgcn_s_setprio(0); SCHED0; } while (0)

// one K-tile = 8 phases. BETA = t&1 (literal), T2A = t+2 staging target.
#define TILE(BETA, T2A, DOSTAGE, RDNEXT, GATE4) do { \
  /* P0: MFMA aX x bP ; read bQ<-B1k0(t) */ \
  READ_B2(bQ, BETA, 1, 0); \
  LGKM(2); EXEC8(aX, bP, 0, 0); BARRIER; SCHED0; \
  /* P1: MFMA aY x bP ; read aZ<-A0k1(t) */ \
  READ_A4(aZ, BETA, 0, 1); \
  LGKM(6); EXEC8(aY, bP, 4, 0); BARRIER; SCHED0; \
  /* P2: MFMA aY x bQ ; read bP<-B0k1(t) */ \
  READ_B2(bP, BETA, 0, 1); \
  LGKM(6); EXEC8(aY, bQ, 4, 2); BARRIER; SCHED0; \
  /* P3: MFMA aX x bQ */ \
  LGKM(6); EXEC8(aX, bQ, 0, 2); BARRIER; SCHED0; \
  /* P4: MFMA aZ x bP ; read aY<-A1k1(t) ; stage A-q0,B-q0 */ \
  READ_A4(aY, BETA, 1, 1); \
  LGKM(4); SCHED0; \
  if (DOSTAGE) { stA(BETA, 0, T2A); stB(BETA, 0, T2A); } \
  EXEC8(aZ, bP, 0, 0); BARRIER; SCHED0; \
  /* P5: MFMA aY x bP ; read bQ<-B1k1(t) ; stage A-q1,B-q1 ; vmcnt gate */ \
  READ_B2(bQ, BETA, 1, 1); \
  LGKM(2); SCHED0; \
  if (DOSTAGE) { stA(BETA, 1, T2A); stB(BETA, 1, T2A); } \
  EXEC8(aY, bP, 4, 0); \
  if (GATE4) asm volatile("s_waitcnt vmcnt(4)"); \
  else       asm volatile("s_waitcnt vmcnt(0)"); \
  BARRIER; SCHED0; \
  /* P6: MFMA aY x bQ ; read aX<-A0k0(t+1), bP<-B0k0(t+1) ; stage A-q2,B-q2 */ \
  if (RDNEXT) { READ_A4(aX, (BETA)^1, 0, 0); READ_B2(bP, (BETA)^1, 0, 0); LGKM(6); } \
  else LGKM(0); \
  SCHED0; \
  if (DOSTAGE) { stA(BETA, 2, T2A); stB(BETA, 2, T2A); } \
  EXEC8(aY, bQ, 4, 2); BARRIER; SCHED0; \
  /* P7: MFMA aZ x bQ ; read aY<-A1k0(t+1) ; stage A-q3,B-q3 */ \
  if (RDNEXT) { READ_A4(aY, (BETA)^1, 1, 0); LGKM(10); } \
  else LGKM(0); \
  SCHED0; \
  if (DOSTAGE) { stA(BETA, 3, T2A); stB(BETA, 3, T2A); } \
  EXEC8(aZ, bQ, 0, 2); BARRIER; SCHED0; \
} while (0)

template<int MODE>
__global__ __launch_bounds__(512, 2) void gemm_bt(
    const u16* __restrict__ A, const u16* __restrict__ W,
    float* __restrict__ Cf, u16* __restrict__ Cb,
    const u16* __restrict__ R, int N, int K)
{
  __shared__ __align__(16) u16 ldsA[2][256 * 64];   // 64 KB
  __shared__ __align__(16) u16 ldsB[2][256 * 64];   // 64 KB (permuted layout)

  const int tid  = threadIdx.x;
  const int wave = tid >> 6;
  const int lane = tid & 63;
  const int wmi  = wave >> 2;          // 0..1 : wave M row (128 rows each)
  const int wni  = wave & 3;           // 0..3 : wave N col (64 cols each)
  const int lm   = lane & 15;
  const int lq   = lane >> 4;

  // tile swizzle (grid.x = M/256, divisible by GROUP_M; grid.y = N-tiles)
  const int bid  = blockIdx.x + blockIdx.y * gridDim.x;
  const int gsz  = GROUP_M * gridDim.y;
  const int gid  = bid / gsz;
  const int rem  = bid - gid * gsz;
  const int bm   = (gid * GROUP_M + (rem % GROUP_M)) * 256;
  const int bn   = (rem / GROUP_M) * 256;

  const int NT = K >> 6;               // K-tiles of 64 (NT even, >= 4)

  // staging: round q = 64 LDS rows; wave w writes rows q*64+w*8 .. +8.
  // source chunk pre-swizzle: LDS chunk (lane&7) <- global chunk (lane&7)^(lane>>3)
  const int ls     = lane >> 3;
  const int schunk = (lane & 7) ^ ls;
  const int rowA   = wave * 8 + ls;                              // A: rho == global row
  const int rowB   = (wave >> 2) * 64 + (wave & 3) * 8 + ls;     // B: base of permuted map
  const u16* gA = A + (size_t)(bm + rowA) * K + schunk * 8;
  const u16* gB = W + (size_t)(bn + rowB) * K + schunk * 8;
  const size_t rowK = (size_t)64 * K;

  auto stA = [&](int buf, int q, int t2) {
    async16(gA + (size_t)t2 * 64 + (size_t)q * rowK,
            &ldsA[buf][(q * 64 + wave * 8) * 64]);
  };
  // B permuted: LDS rho = half*128 + band*32 + r ; global row = band*64+half*32+r
  // => per-q global row delta from rowB: {0,128,32,160}
  auto stB = [&](int buf, int q, int t2) {
    const int qrow = (q == 0) ? 0 : (q == 1) ? 128 : (q == 2) ? 32 : 160;
    async16(gB + (size_t)t2 * 64 + (size_t)qrow * K,
            &ldsB[buf][(q * 64 + wave * 8) * 64]);
  };

  const unsigned lAbase =
      (unsigned)(size_t)(const __attribute__((address_space(3))) u16*)&ldsA[0][0];
  const unsigned lBbase =
      (unsigned)(size_t)(const __attribute__((address_space(3))) u16*)&ldsB[0][0];
  // A frag: row = wmi*128 + mi*16 + lm, byte = row*128 + ((lq+4kh)^(lm&7))*16
  const unsigned aAddr0 = lAbase + (unsigned)((wmi * 128 + lm) * 128 + (((lq    ) ^ (lm & 7)) * 16));
  const unsigned aAddr1 = lAbase + (unsigned)((wmi * 128 + lm) * 128 + (((lq + 4) ^ (lm & 7)) * 16));
  // B frag: rho = np*128 + wni*32 + ni*16 + lm  (np,ni via offset imm)
  const unsigned bAddr0 = lBbase + (unsigned)((wni * 32 + lm) * 128 + (((lq    ) ^ (lm & 7)) * 16));
  const unsigned bAddr1 = lBbase + (unsigned)((wni * 32 + lm) * 128 + (((lq + 4) ^ (lm & 7)) * 16));

  f32x4 acc[8][4] = {};
  f32x4 aX[4], aY[4], aZ[4], bP[2], bQ[2];   // static-indexed banks (64 regs)

  // ---------------- prologue: stage tiles 0,1 fully; preload aX,aY,bP
  stA(0, 0, 0); stA(0, 1, 0); stA(0, 2, 0); stA(0, 3, 0);
  stB(0, 0, 0); stB(0, 1, 0); stB(0, 2, 0); stB(0, 3, 0);
  stA(1, 0, 1); stA(1, 1, 1); stA(1, 2, 1); stA(1, 3, 1);
  stB(1, 0, 1); stB(1, 1, 1); stB(1, 2, 1); stB(1, 3, 1);
  asm volatile("s_waitcnt vmcnt(0)");
  BARRIER;
  READ_A4(aX, 0, 0, 0);     // A0k0(0)
  READ_A4(aY, 0, 1, 0);     // A1k0(0)
  READ_B2(bP, 0, 0, 0);     // B0k0(0)
  SCHED0;                   // P0's LGKM(2) drains these 10 (2 own in flight)

  // ---------------- main loop: tiles 0 .. NT-3 staged+full (2 per iter)
  for (int t = 0; t + 3 < NT; t += 2) {
    TILE(0, t + 2, 1, 1, 1);
    TILE(1, t + 3, 1, 1, 1);
  }

  // ---------------- tail: tiles NT-2, NT-1; no staging; vmcnt(0) gates
  TILE(0, 0, 0, 1, 0);
  TILE(1, 0, 0, 0, 0);

  // epilogue. C/D layout (verified m89/m91): col = lane&15, row = (lane>>4)*4 + reg
  const int row0 = bm + wmi * 128 + lq * 4;
  const int col0 = bn + wni * 64 + lm;
#pragma unroll
  for (int mi = 0; mi < 8; ++mi)
#pragma unroll
    for (int ni = 0; ni < 4; ++ni) {
      size_t base = (size_t)(row0 + mi * 16) * N + (col0 + ni * 16);
#pragma unroll
      for (int r2 = 0; r2 < 4; ++r2) {
        size_t idx = base + (size_t)r2 * N;
        float v = acc[mi][ni][r2];
        if (MODE == 0) Cf[idx] = v;
        if (MODE == 2) { float rl = v > 0.f ? v : 0.f; Cb[idx] = f2bf(rl * rl); }
        if (MODE == 3) Cb[idx] = f2bf(v);
        if (MODE == 4) Cf[idx] += sigm(bf2f(R[idx])) * v;
      }
    }
}

// ---------------------------------------------------------------------------
// LayerNorm both rows t and t-1, time-shift mix, bf16 cast.
// One block per row (b,t). ov/oxb may be null (phase-2 use).
// oxb (raw x cast) is written at pitch 2*CC (the A' interleaved buffer).
// ---------------------------------------------------------------------------
__global__ __launch_bounds__(256) void prep_mix(
    const float* __restrict__ x,
    const float* __restrict__ lnw, const float* __restrict__ lnb,
    const float* __restrict__ mk, const float* __restrict__ mv, const float* __restrict__ mr,
    u16* __restrict__ ok, u16* __restrict__ ov, u16* __restrict__ orr,
    u16* __restrict__ oxb)
{
  const int m = blockIdx.x;
  const int t = m & (TT - 1);
  const int tid = threadIdx.x;
  const int wave = tid >> 6, lane = tid & 63;
  const bool hasp = (t != 0);

  const float4 xc4 = ((const float4*)(x + (size_t)m * CC))[tid];
  float4 xp4 = make_float4(0.f, 0.f, 0.f, 0.f);
  if (hasp) xp4 = ((const float4*)(x + (size_t)(m - 1) * CC))[tid];

  float s0 = xc4.x + xc4.y + xc4.z + xc4.w;
  float s1 = xc4.x*xc4.x + xc4.y*xc4.y + xc4.z*xc4.z + xc4.w*xc4.w;
  float s2 = xp4.x + xp4.y + xp4.z + xp4.w;
  float s3 = xp4.x*xp4.x + xp4.y*xp4.y + xp4.z*xp4.z + xp4.w*xp4.w;
#pragma unroll
  for (int off2 = 32; off2 > 0; off2 >>= 1) {
    s0 += __shfl_xor(s0, off2);
    s1 += __shfl_xor(s1, off2);
    s2 += __shfl_xor(s2, off2);
    s3 += __shfl_xor(s3, off2);
  }
  __shared__ float red[4][4];
  if (lane == 0) { red[0][wave] = s0; red[1][wave] = s1; red[2][wave] = s2; red[3][wave] = s3; }
  __syncthreads();
  const float S0 = red[0][0] + red[0][1] + red[0][2] + red[0][3];
  const float S1 = red[1][0] + red[1][1] + red[1][2] + red[1][3];
  const float S2 = red[2][0] + red[2][1] + red[2][2] + red[2][3];
  const float S3 = red[3][0] + red[3][1] + red[3][2] + red[3][3];
  const float inv = 1.f / (float)CC;
  const float muc = S0 * inv, varc = S1 * inv - muc * muc, rsc = rsqrtf(varc + 1e-5f);
  const float mup = S2 * inv, varp = S3 * inv - mup * mup, rsp = rsqrtf(varp + 1e-5f);

  const float xc[4] = {xc4.x, xc4.y, xc4.z, xc4.w};
  const float xp[4] = {xp4.x, xp4.y, xp4.z, xp4.w};
  const float4 lw4 = ((const float4*)lnw)[tid];
  const float4 lb4 = ((const float4*)lnb)[tid];
  const float lw[4] = {lw4.x, lw4.y, lw4.z, lw4.w};
  const float lb[4] = {lb4.x, lb4.y, lb4.z, lb4.w};
  const float4 mk4 = ((const float4*)mk)[tid];
  const float mka[4] = {mk4.x, mk4.y, mk4.z, mk4.w};
  const float4 mr4 = ((const float4*)mr)[tid];
  const float mra[4] = {mr4.x, mr4.y, mr4.z, mr4.w};
  float mva[4] = {0.f, 0.f, 0.f, 0.f};
  if (ov) {
    const float4 mv4 = ((const float4*)mv)[tid];
    mva[0] = mv4.x; mva[1] = mv4.y; mva[2] = mv4.z; mva[3] = mv4.w;
  }

  ushort4 wk2, wv2, wr2, wb2;
  u16* pk = (u16*)&wk2; u16* pv = (u16*)&wv2; u16* pr = (u16*)&wr2; u16* pb = (u16*)&wb2;
#pragma unroll
  for (int j = 0; j < 4; ++j) {
    float h  = (xc[j] - muc) * rsc * lw[j] + lb[j];
    float hh = hasp ? (xp[j] - mup) * rsp * lw[j] + lb[j] : 0.f;
    pk[j] = f2bf(h * mka[j] + hh * (1.f - mka[j]));
    pv[j] = f2bf(h * mva[j] + hh * (1.f - mva[j]));
    pr[j] = f2bf(h * mra[j] + hh * (1.f - mra[j]));
    pb[j] = f2bf(xc[j]);
  }
  ((ushort4*)(ok + (size_t)m * CC))[tid] = wk2;
  if (ov)  ((ushort4*)(ov  + (size_t)m * CC))[tid] = wv2;
  ((ushort4*)(orr + (size_t)m * CC))[tid] = wr2;
  if (oxb) ((ushort4*)(oxb + (size_t)m * (2 * CC)))[tid] = wb2;   // A' xb half
}

// ---------------------------------------------------------------------------
// WKV blocked 3-phase parallel scan. Output goes to the rwkv half of the
// interleaved A' buffer: out pitch = 2*CC.
// ---------------------------------------------------------------------------
#define WKV_CPB 32
#define WKV_NCH 32
#define WKV_L   (TT / WKV_NCH)   // 64

__global__ __launch_bounds__(1024) void wkv_scan(
    const u16* __restrict__ k, const u16* __restrict__ v, const u16* __restrict__ r,
    const float* __restrict__ decay, const float* __restrict__ first,
    u16* __restrict__ out)   // points at A' + CC (rwkv half), pitch 2*CC
{
  const int b  = blockIdx.x >> 5;
  const int c0 = (blockIdx.x & 31) * WKV_CPB;
  const int tid = threadIdx.x;
  const int cl = tid & 31;
  const int j  = tid >> 5;
  const int c  = c0 + cl;

  const float w   = -__expf(decay[c]);
  const float lam = __expf(w);
  const float eu  = __expf(first[c]);

  const size_t base  = (size_t)b * TT * CC + (size_t)j * WKV_L * CC + c;
  size_t obase = ((size_t)b * TT + (size_t)j * WKV_L) * (2 * CC) + c;

  // phase 1: local scan (state only)
  float a = 0.f, bb = 0.f;
  size_t idx = base;
  for (int i = 0; i < WKV_L; ++i, idx += CC) {
    const float kt = bf2f(k[idx]), vt = bf2f(v[idx]);
    const float ek = __expf(kt);
    a  = fmaf(lam, a, ek * vt);
    bb = fmaf(lam, bb, ek);
  }

  // phase 2: exclusive carry scan over chunks
  __shared__ float sA[WKV_NCH][WKV_CPB];
  __shared__ float sB[WKV_NCH][WKV_CPB];
  sA[j][cl] = a; sB[j][cl] = bb;
  __syncthreads();
  if (tid < WKV_CPB) {
    float ca = 0.f, cb = 0.f;
    const float cw   = -__expf(decay[c0 + tid]);
    const float cLam = __expf(cw * (float)WKV_L);
#pragma unroll
    for (int q = 0; q < WKV_NCH; ++q) {
      const float ta = sA[q][tid], tb = sB[q][tid];
      sA[q][tid] = ca; sB[q][tid] = cb;
      ca = fmaf(cLam, ca, ta);
      cb = fmaf(cLam, cb, tb);
    }
  }
  __syncthreads();
  a = sA[j][cl]; bb = sB[j][cl];

  // phase 3: replay with carry-in, emit sigmoid(r)*y into A' rwkv half
  idx = base;
  for (int i = 0; i < WKV_L; ++i, idx += CC, obase += 2 * CC) {
    const float kt = bf2f(k[idx]), vt = bf2f(v[idx]), rt = bf2f(r[idx]);
    const float ek = __expf(kt);
    const float e2 = eu * ek;
    const float y  = (a + e2 * vt) / (bb + e2);
    out[obase] = f2bf(sigm(rt) * y);
    a  = fmaf(lam, a, ek * vt);
    bb = fmaf(lam, bb, ek);
  }
}

// ---------------------------------------------------------------------------
// Weight f32 -> bf16 conversion. Segments 3 (Wo) and 4 (Wsh) are interleaved
// into W' = [Wsh | Wo] rows of pitch 2048 for the merged short+Wo GEMM.
// ---------------------------------------------------------------------------
struct ConvArgs { const float* src[8]; int end[8]; int dstoff[8]; };

__global__ __launch_bounds__(256) void conv_w(ConvArgs args, u16* __restrict__ dst)
{
  const int i = (blockIdx.x * 256 + threadIdx.x) * 4;
  int seg = 0;
  const float* sp = args.src[0];
  int base = 0;
#pragma unroll
  for (int s = 1; s < 8; ++s) {
    if (i >= args.end[s - 1]) { seg = s; sp = args.src[s]; base = args.end[s - 1]; }
  }
  const int l = i - base;
  const float4 vv = *(const float4*)(sp + l);
  int dsti;
  if (seg == 3)      { int row = l >> 10, col = l & 1023; dsti = args.dstoff[3] + row * 2048 + 1024 + col; }
  else if (seg == 4) { int row = l >> 10, col = l & 1023; dsti = args.dstoff[4] + row * 2048 + col; }
  else               dsti = args.dstoff[seg] + l;
  ushort4 d;
  d.x = f2bf(vv.x); d.y = f2bf(vv.y); d.z = f2bf(vv.z); d.w = f2bf(vv.w);
  *(ushort4*)(dst + dsti) = d;
}

extern "C" void kernel_launch(void* const* d_in, const int* in_sizes, int n_in,
                              void* d_out, int out_size, void* d_ws, size_t ws_size,
                              hipStream_t stream)
{
  const float* x    = (const float*)d_in[0];
  const float* ln1w = (const float*)d_in[1];
  const float* ln1b = (const float*)d_in[2];
  const float* ln2w = (const float*)d_in[3];
  const float* ln2b = (const float*)d_in[4];
  const float* tdec = (const float*)d_in[5];
  const float* tfir = (const float*)d_in[6];
  const float* amk  = (const float*)d_in[7];
  const float* amv  = (const float*)d_in[8];
  const float* amr  = (const float*)d_in[9];
  const float* Wk   = (const float*)d_in[10];
  const float* Wv   = (const float*)d_in[11];
  const float* Wr   = (const float*)d_in[12];
  const float* Wo   = (const float*)d_in[13];
  const float* fmk  = (const float*)d_in[14];
  const float* fmr  = (const float*)d_in[15];
  const float* WfK  = (const float*)d_in[16];
  const float* WfR  = (const float*)d_in[17];
  const float* WfV  = (const float*)d_in[18];
  const float* Wsh  = (const float*)d_in[19];
  float* out = (float*)d_out;
  char* ws = (char*)d_ws;

  // workspace: 28 MB bf16 weights + six 32 MB regions = 230,686,720 B total.
  u16* wW = (u16*)(ws);
  u16* U0 = (u16*)(ws + 29360128);
  u16* U1 = (u16*)(ws + 62914560);
  u16* U2 = (u16*)(ws + 96468992);
  u16* U3 = (u16*)(ws + 130023424);
  u16* U4 = (u16*)(ws + 163577856);   // A' = U4+U5, 64 MB contiguous

  // liveness-based aliases:
  u16* xk   = U0;          // prep1
  u16* xv   = U1;
  u16* xr   = U2;
  u16* Ap   = U4;          // A' [M, 2C]: cols 0..C-1 = bf16(x), C..2C-1 = rwkv
  u16* kbuf = U3;          // k = xk*Wk   (U0 dead after)
  u16* vbuf = U0;          // v = xv*Wv   (U1 dead after)
  u16* rbuf = U1;          // r = xr*Wr   (U2 dead after)
  u16* gk   = U0;          // prep2       (U0 dead after wkv)
  u16* gr   = U1;
  u16* kkb  = U2;          // kk [M,F] bf16 = 128 MB, spans U2..U5 (all dead)
  u16* rffn = U0;          // r_ffn       (gk/U0 dead after kk GEMM)

  u16* bWk   = wW + 0;
  u16* bWv   = wW + 1048576;
  u16* bWr   = wW + 2097152;
  u16* bWsWo = wW + 3145728;   // W' [C, 2C] interleaved [Wsh | Wo]
  u16* bWfR  = wW + 5242880;
  u16* bWfK  = wW + 6291456;
  u16* bWfV  = wW + 10485760;

  ConvArgs ca;
  ca.src[0] = Wk;  ca.src[1] = Wv;  ca.src[2] = Wr;  ca.src[3] = Wo;
  ca.src[4] = Wsh; ca.src[5] = WfR; ca.src[6] = WfK; ca.src[7] = WfV;
  const int e = 1048576;
  ca.end[0] = e;     ca.end[1] = 2*e;  ca.end[2] = 3*e;  ca.end[3] = 4*e;
  ca.end[4] = 5*e;   ca.end[5] = 6*e;  ca.end[6] = 10*e; ca.end[7] = 14*e;
  ca.dstoff[0] = 0;     ca.dstoff[1] = e;    ca.dstoff[2] = 2*e;
  ca.dstoff[3] = 3*e;   ca.dstoff[4] = 3*e;  // both into W' (interleaved)
  ca.dstoff[5] = 5*e;   ca.dstoff[6] = 6*e;  ca.dstoff[7] = 10*e;

  conv_w<<<14336, 256, 0, stream>>>(ca, wW);
  prep_mix<<<MM, 256, 0, stream>>>(x, ln1w, ln1b, amk, amv, amr, xk, xv, xr, Ap);

  dim3 g8(MM / 256, CC / 256);
  gemm_bt<3><<<g8, 512, 0, stream>>>(xk, bWk, nullptr, kbuf, nullptr, CC, CC);
  gemm_bt<3><<<g8, 512, 0, stream>>>(xv, bWv, nullptr, vbuf, nullptr, CC, CC);
  gemm_bt<3><<<g8, 512, 0, stream>>>(xr, bWr, nullptr, rbuf, nullptr, CC, CC);

  wkv_scan<<<BB * (CC / WKV_CPB), 1024, 0, stream>>>(kbuf, vbuf, rbuf, tdec, tfir, Ap + CC);

  // out = [xb | rwkv] * [Wsh | Wo]^T   (single K=2048 GEMM)
  gemm_bt<0><<<g8, 512, 0, stream>>>(Ap, bWsWo, out, nullptr, nullptr, CC, 2 * CC);

  prep_mix<<<MM, 256, 0, stream>>>(out, ln2w, ln2b, fmk, nullptr, fmr, gk, nullptr, gr, nullptr);

  dim3 gF(MM / 256, FF / 256);
  gemm_bt<2><<<gF, 512, 0, stream>>>(gk, bWfK, nullptr, kkb, nullptr, FF, CC);  // kk = relu(gk*WfK)^2
  gemm_bt<3><<<g8, 512, 0, stream>>>(gr, bWfR, nullptr, rffn, nullptr, CC, CC);
  // out += sigm(rffn) * (kk * WfV)   (fused final_add)
  gemm_bt<4><<<g8, 512, 0, stream>>>(kkb, bWfV, out, nullptr, rffn, CC, FF);
}

// Round 5
// 796.351 us; speedup vs baseline: 2.2811x; 1.1626x over previous
//
#include <hip/hip_runtime.h>

#define BB 8
#define TT 2048
#define CC 1024
#define FF 4096
#define MM (BB*TT)   // 16384

typedef unsigned short u16;
typedef __bf16 bf16x8 __attribute__((ext_vector_type(8)));
typedef float f32x4 __attribute__((ext_vector_type(4)));

__device__ __forceinline__ u16 f2bf(float f) {
  unsigned int u = __float_as_uint(f);
  u += 0x7fffu + ((u >> 16) & 1u);     // RNE to bf16
  return (u16)(u >> 16);
}
__device__ __forceinline__ float bf2f(u16 h) {
  unsigned int u = ((unsigned int)h) << 16;
  return __uint_as_float(u);
}
__device__ __forceinline__ float sigm(float x) { return 1.f / (1.f + __expf(-x)); }

__device__ __forceinline__ void async16(const void* g, void* l) {
  __builtin_amdgcn_global_load_lds(
      (const __attribute__((address_space(1))) unsigned int*)g,
      (__attribute__((address_space(3))) unsigned int*)l, 16, 0, 0);
}

// ---------------------------------------------------------------------------
// NT GEMM: C[m,n] = sum_k A[m,k]*W[n,k], A [M,K] bf16 row-major, W [N,K] bf16.
//
// 256x256 tile, BK=64, 512 thr (8 waves 2Mx4N; per wave 128x64 out = 8x4
// frags of 16x16x32 MFMA). 8 phases/K-tile, 8 MFMA each, but only TWO
// barriers per tile (end-P2, end-P4) so waves drift and the LDS-read stream
// overlaps the MFMA stream (round-1/4 lesson: per-phase barriers lockstep
// the CU into serial {read-burst, MFMA}; LDS ~2048cyc/tile == MFMA time,
// so overlap is the whole game). Banks: aA,aB (4 frags, 16 regs) +
// bP,bQ,bR,bS (2 frags, 8 regs) = 64 frag regs -> ~208 total, no spill
// (round-3/4 lesson).
//
// Use-sequence  P0:aA.bP P1:aA.bQ P2:aB.bQ P3:aB.bP P4:aA.bR P5:aA.bS
//               P6:aB.bS P7:aB.bR   (aA=M0, aB=M1; kh0 P0-3, kh1 P4-7)
// Reads (1-2 phases ahead, counted lgkm gates; chain verified closed):
//   P0:aB(M1k0) P1:bR(k1) P2:aA(M0k1) P3:bS(k1) P4:aB(M1k1)
//   P5:bP(t+1)  P6:aA(t+1 M0k0)  P7:bQ(t+1)     gates 6,6,6,6,6,6,6,8
// Region liveness (cur buf): B-q01 last read P1, A-q0/q2 last P2 ->
//   barrier end-P2, stage both at P3. B-q23 last P3, A-q1/q3 last P4 ->
//   barrier end-P4, stage at P5. Next-tile reads (P5..P2') covered by
//   vmcnt(4) at end-P4 (leaves exactly P3(t)'s 4 stages in flight; drains
//   P3(t-1)+P5(t-1) which wrote everything read through P4(t+1)).
// Tail: NT-2 {ST=0,RD=1,vmcnt(0)}, NT-1 {ST=0,RD=0, lgkm 4/0/0}.
// B LDS layout permuted [half][band][32rows]; chunk^row&7 source-side XOR
// swizzle; staging maps identical to rounds 3/4 (correctness-proven).
// MODE 0: Cf[idx] = v (f32).      MODE 2: Cb[idx] = bf16(relu(v)^2).
// MODE 3: Cb[idx] = bf16(v).      MODE 4: Cf[idx] += sigm(R[idx]) * v.
// ---------------------------------------------------------------------------
#define GROUP_M 16

#define DSRD(d, a, o) \
  asm volatile("ds_read_b128 %0, %1 offset:%c2" : "=v"(d) : "v"(a), "i"(o))

#define MFMA16(A_, B_, C_) \
  (C_) = __builtin_amdgcn_mfma_f32_16x16x32_bf16( \
      __builtin_bit_cast(bf16x8, (A_)), __builtin_bit_cast(bf16x8, (B_)), (C_), 0, 0, 0)

#define SCHED0  __builtin_amdgcn_sched_barrier(0)
#define BARRIER __builtin_amdgcn_s_barrier()
#define LGKM(n) asm volatile("s_waitcnt lgkmcnt(" #n ")")

#define READ_A4(bank, BETA, MH, KH) do { \
  DSRD(bank[0], aAddr##KH, (BETA)*32768 + ((MH)*4+0)*2048); \
  DSRD(bank[1], aAddr##KH, (BETA)*32768 + ((MH)*4+1)*2048); \
  DSRD(bank[2], aAddr##KH, (BETA)*32768 + ((MH)*4+2)*2048); \
  DSRD(bank[3], aAddr##KH, (BETA)*32768 + ((MH)*4+3)*2048); \
} while (0)

#define READ_B2(bank, BETA, NP, KH) do { \
  DSRD(bank[0], bAddr##KH, (BETA)*32768 + (NP)*16384 + 0*2048); \
  DSRD(bank[1], bAddr##KH, (BETA)*32768 + (NP)*16384 + 1*2048); \
} while (0)

#define MFMA8(ABANK, BBANK, AO, NO) do { \
  _Pragma("unroll") \
  for (int mi = 0; mi < 4; ++mi) \
    _Pragma("unroll") \
    for (int ni = 0; ni < 2; ++ni) \
      MFMA16(ABANK[mi], BBANK[ni], acc[(AO)+mi][(NO)+ni]); \
} while (0)

#define EXEC8(ABANK, BBANK, AO, NO) do { \
  __builtin_amdgcn_s_setprio(1); \
  MFMA8(ABANK, BBANK, AO, NO); \
  __builtin_amdgcn_s_setprio(0); SCHED0; } while (0)

// one K-tile = 8 phases, 2 barriers. BETA literal, T2A = t+2 staging target.
#define TILE(BETA, T2A, ST, RD) do { \
  /* P0 */ READ_A4(aB, BETA, 1, 0); \
  LGKM(6); SCHED0; EXEC8(aA, bP, 0, 0); \
  /* P1 */ READ_B2(bR, BETA, 0, 1); \
  LGKM(6); SCHED0; EXEC8(aA, bQ, 0, 2); \
  /* P2 */ READ_A4(aA, BETA, 0, 1); \
  LGKM(6); SCHED0; EXEC8(aB, bQ, 4, 2); \
  BARRIER; SCHED0; \
  /* P3: stage B-q01 + A-q0,q2 (t+2) after end-P2 barrier */ \
  READ_B2(bS, BETA, 1, 1); \
  if (ST) { stB(BETA, 0, T2A); stB(BETA, 1, T2A); \
            stA(BETA, 0, T2A); stA(BETA, 2, T2A); } \
  LGKM(6); SCHED0; EXEC8(aB, bP, 4, 0); \
  /* P4 */ READ_A4(aB, BETA, 1, 1); \
  LGKM(6); SCHED0; EXEC8(aA, bR, 0, 0); \
  if (ST) asm volatile("s_waitcnt vmcnt(4)"); \
  else    asm volatile("s_waitcnt vmcnt(0)"); \
  BARRIER; SCHED0; \
  /* P5: stage B-q23 + A-q1,q3 (t+2) after end-P4 barrier */ \
  if (RD) READ_B2(bP, (BETA)^1, 0, 0); \
  if (ST) { stB(BETA, 2, T2A); stB(BETA, 3, T2A); \
            stA(BETA, 1, T2A); stA(BETA, 3, T2A); } \
  if (RD) LGKM(6); else LGKM(4); \
  SCHED0; EXEC8(aA, bS, 0, 2); \
  /* P6 */ if (RD) { READ_A4(aA, (BETA)^1, 0, 0); LGKM(6); } else LGKM(0); \
  SCHED0; EXEC8(aB, bS, 4, 2); \
  /* P7 */ if (RD) { READ_B2(bQ, (BETA)^1, 1, 0); LGKM(8); } else LGKM(0); \
  SCHED0; EXEC8(aB, bR, 4, 0); \
} while (0)

template<int MODE>
__global__ __launch_bounds__(512, 2) void gemm_bt(
    const u16* __restrict__ A, const u16* __restrict__ W,
    float* __restrict__ Cf, u16* __restrict__ Cb,
    const u16* __restrict__ R, int N, int K)
{
  __shared__ __align__(16) u16 ldsA[2][256 * 64];   // 64 KB
  __shared__ __align__(16) u16 ldsB[2][256 * 64];   // 64 KB (permuted layout)

  const int tid  = threadIdx.x;
  const int wave = tid >> 6;
  const int lane = tid & 63;
  const int wmi  = wave >> 2;          // 0..1 : wave M row (128 rows each)
  const int wni  = wave & 3;           // 0..3 : wave N col (64 cols each)
  const int lm   = lane & 15;
  const int lq   = lane >> 4;

  // tile swizzle (grid.x = M/256, divisible by GROUP_M; grid.y = N-tiles)
  const int bid  = blockIdx.x + blockIdx.y * gridDim.x;
  const int gsz  = GROUP_M * gridDim.y;
  const int gid  = bid / gsz;
  const int rem  = bid - gid * gsz;
  const int bm   = (gid * GROUP_M + (rem % GROUP_M)) * 256;
  const int bn   = (rem / GROUP_M) * 256;

  const int NT = K >> 6;               // K-tiles of 64 (NT even, >= 4)

  // staging: round q = 64 LDS rows; wave w writes rows q*64+w*8 .. +8.
  // source chunk pre-swizzle: LDS chunk (lane&7) <- global chunk (lane&7)^(lane>>3)
  const int ls     = lane >> 3;
  const int schunk = (lane & 7) ^ ls;
  const int rowA   = wave * 8 + ls;                              // A: rho == global row
  const int rowB   = (wave >> 2) * 64 + (wave & 3) * 8 + ls;     // B: base of permuted map
  const u16* gA = A + (size_t)(bm + rowA) * K + schunk * 8;
  const u16* gB = W + (size_t)(bn + rowB) * K + schunk * 8;
  const size_t rowK = (size_t)64 * K;

  auto stA = [&](int buf, int q, int t2) {
    async16(gA + (size_t)t2 * 64 + (size_t)q * rowK,
            &ldsA[buf][(q * 64 + wave * 8) * 64]);
  };
  // B permuted: LDS rho = half*128 + band*32 + r ; global row = band*64+half*32+r
  // => per-q global row delta from rowB: {0,128,32,160}
  auto stB = [&](int buf, int q, int t2) {
    const int qrow = (q == 0) ? 0 : (q == 1) ? 128 : (q == 2) ? 32 : 160;
    async16(gB + (size_t)t2 * 64 + (size_t)qrow * K,
            &ldsB[buf][(q * 64 + wave * 8) * 64]);
  };

  const unsigned lAbase =
      (unsigned)(size_t)(const __attribute__((address_space(3))) u16*)&ldsA[0][0];
  const unsigned lBbase =
      (unsigned)(size_t)(const __attribute__((address_space(3))) u16*)&ldsB[0][0];
  // A frag: row = wmi*128 + mi*16 + lm, byte = row*128 + ((lq+4kh)^(lm&7))*16
  const unsigned aAddr0 = lAbase + (unsigned)((wmi * 128 + lm) * 128 + (((lq    ) ^ (lm & 7)) * 16));
  const unsigned aAddr1 = lAbase + (unsigned)((wmi * 128 + lm) * 128 + (((lq + 4) ^ (lm & 7)) * 16));
  // B frag: rho = np*128 + wni*32 + ni*16 + lm  (np,ni via offset imm)
  const unsigned bAddr0 = lBbase + (unsigned)((wni * 32 + lm) * 128 + (((lq    ) ^ (lm & 7)) * 16));
  const unsigned bAddr1 = lBbase + (unsigned)((wni * 32 + lm) * 128 + (((lq + 4) ^ (lm & 7)) * 16));

  f32x4 acc[8][4] = {};
  f32x4 aA[4], aB[4], bP[2], bQ[2], bR[2], bS[2];   // 64 frag regs

  // ---------------- prologue: stage tiles 0,1; preload aA(M0k0), bP, bQ
  stA(0, 0, 0); stA(0, 1, 0); stA(0, 2, 0); stA(0, 3, 0);
  stB(0, 0, 0); stB(0, 1, 0); stB(0, 2, 0); stB(0, 3, 0);
  stA(1, 0, 1); stA(1, 1, 1); stA(1, 2, 1); stA(1, 3, 1);
  stB(1, 0, 1); stB(1, 1, 1); stB(1, 2, 1); stB(1, 3, 1);
  asm volatile("s_waitcnt vmcnt(0)");
  BARRIER;
  READ_A4(aA, 0, 0, 0);     // M0k0(0)
  READ_B2(bP, 0, 0, 0);     // n01k0(0)
  READ_B2(bQ, 0, 1, 0);     // n23k0(0)
  LGKM(0); SCHED0;

  // ---------------- main loop: tiles 0 .. NT-3 staged+full (2 per iter)
  for (int t = 0; t + 3 < NT; t += 2) {
    TILE(0, t + 2, 1, 1);
    TILE(1, t + 3, 1, 1);
  }

  // ---------------- tail: tiles NT-2, NT-1
  TILE(0, 0, 0, 1);
  TILE(1, 0, 0, 0);

  // epilogue. C/D layout (verified m89/m91): col = lane&15, row = (lane>>4)*4 + reg
  const int row0 = bm + wmi * 128 + lq * 4;
  const int col0 = bn + wni * 64 + lm;
#pragma unroll
  for (int mi = 0; mi < 8; ++mi)
#pragma unroll
    for (int ni = 0; ni < 4; ++ni) {
      size_t base = (size_t)(row0 + mi * 16) * N + (col0 + ni * 16);
#pragma unroll
      for (int r2 = 0; r2 < 4; ++r2) {
        size_t idx = base + (size_t)r2 * N;
        float v = acc[mi][ni][r2];
        if (MODE == 0) Cf[idx] = v;
        if (MODE == 2) { float rl = v > 0.f ? v : 0.f; Cb[idx] = f2bf(rl * rl); }
        if (MODE == 3) Cb[idx] = f2bf(v);
        if (MODE == 4) Cf[idx] += sigm(bf2f(R[idx])) * v;
      }
    }
}

// ---------------------------------------------------------------------------
// LayerNorm both rows t and t-1, time-shift mix, bf16 cast.
// One block per row (b,t). ov/oxb may be null (phase-2 use).
// oxb (raw x cast) is written at pitch 2*CC (the A' interleaved buffer).
// ---------------------------------------------------------------------------
__global__ __launch_bounds__(256) void prep_mix(
    const float* __restrict__ x,
    const float* __restrict__ lnw, const float* __restrict__ lnb,
    const float* __restrict__ mk, const float* __restrict__ mv, const float* __restrict__ mr,
    u16* __restrict__ ok, u16* __restrict__ ov, u16* __restrict__ orr,
    u16* __restrict__ oxb)
{
  const int m = blockIdx.x;
  const int t = m & (TT - 1);
  const int tid = threadIdx.x;
  const int wave = tid >> 6, lane = tid & 63;
  const bool hasp = (t != 0);

  const float4 xc4 = ((const float4*)(x + (size_t)m * CC))[tid];
  float4 xp4 = make_float4(0.f, 0.f, 0.f, 0.f);
  if (hasp) xp4 = ((const float4*)(x + (size_t)(m - 1) * CC))[tid];

  float s0 = xc4.x + xc4.y + xc4.z + xc4.w;
  float s1 = xc4.x*xc4.x + xc4.y*xc4.y + xc4.z*xc4.z + xc4.w*xc4.w;
  float s2 = xp4.x + xp4.y + xp4.z + xp4.w;
  float s3 = xp4.x*xp4.x + xp4.y*xp4.y + xp4.z*xp4.z + xp4.w*xp4.w;
#pragma unroll
  for (int off2 = 32; off2 > 0; off2 >>= 1) {
    s0 += __shfl_xor(s0, off2);
    s1 += __shfl_xor(s1, off2);
    s2 += __shfl_xor(s2, off2);
    s3 += __shfl_xor(s3, off2);
  }
  __shared__ float red[4][4];
  if (lane == 0) { red[0][wave] = s0; red[1][wave] = s1; red[2][wave] = s2; red[3][wave] = s3; }
  __syncthreads();
  const float S0 = red[0][0] + red[0][1] + red[0][2] + red[0][3];
  const float S1 = red[1][0] + red[1][1] + red[1][2] + red[1][3];
  const float S2 = red[2][0] + red[2][1] + red[2][2] + red[2][3];
  const float S3 = red[3][0] + red[3][1] + red[3][2] + red[3][3];
  const float inv = 1.f / (float)CC;
  const float muc = S0 * inv, varc = S1 * inv - muc * muc, rsc = rsqrtf(varc + 1e-5f);
  const float mup = S2 * inv, varp = S3 * inv - mup * mup, rsp = rsqrtf(varp + 1e-5f);

  const float xc[4] = {xc4.x, xc4.y, xc4.z, xc4.w};
  const float xp[4] = {xp4.x, xp4.y, xp4.z, xp4.w};
  const float4 lw4 = ((const float4*)lnw)[tid];
  const float4 lb4 = ((const float4*)lnb)[tid];
  const float lw[4] = {lw4.x, lw4.y, lw4.z, lw4.w};
  const float lb[4] = {lb4.x, lb4.y, lb4.z, lb4.w};
  const float4 mk4 = ((const float4*)mk)[tid];
  const float mka[4] = {mk4.x, mk4.y, mk4.z, mk4.w};
  const float4 mr4 = ((const float4*)mr)[tid];
  const float mra[4] = {mr4.x, mr4.y, mr4.z, mr4.w};
  float mva[4] = {0.f, 0.f, 0.f, 0.f};
  if (ov) {
    const float4 mv4 = ((const float4*)mv)[tid];
    mva[0] = mv4.x; mva[1] = mv4.y; mva[2] = mv4.z; mva[3] = mv4.w;
  }

  ushort4 wk2, wv2, wr2, wb2;
  u16* pk = (u16*)&wk2; u16* pv = (u16*)&wv2; u16* pr = (u16*)&wr2; u16* pb = (u16*)&wb2;
#pragma unroll
  for (int j = 0; j < 4; ++j) {
    float h  = (xc[j] - muc) * rsc * lw[j] + lb[j];
    float hh = hasp ? (xp[j] - mup) * rsp * lw[j] + lb[j] : 0.f;
    pk[j] = f2bf(h * mka[j] + hh * (1.f - mka[j]));
    pv[j] = f2bf(h * mva[j] + hh * (1.f - mva[j]));
    pr[j] = f2bf(h * mra[j] + hh * (1.f - mra[j]));
    pb[j] = f2bf(xc[j]);
  }
  ((ushort4*)(ok + (size_t)m * CC))[tid] = wk2;
  if (ov)  ((ushort4*)(ov  + (size_t)m * CC))[tid] = wv2;
  ((ushort4*)(orr + (size_t)m * CC))[tid] = wr2;
  if (oxb) ((ushort4*)(oxb + (size_t)m * (2 * CC)))[tid] = wb2;   // A' xb half
}

// ---------------------------------------------------------------------------
// WKV blocked 3-phase parallel scan. Output goes to the rwkv half of the
// interleaved A' buffer: out pitch = 2*CC.
// ---------------------------------------------------------------------------
#define WKV_CPB 32
#define WKV_NCH 32
#define WKV_L   (TT / WKV_NCH)   // 64

__global__ __launch_bounds__(1024) void wkv_scan(
    const u16* __restrict__ k, const u16* __restrict__ v, const u16* __restrict__ r,
    const float* __restrict__ decay, const float* __restrict__ first,
    u16* __restrict__ out)   // points at A' + CC (rwkv half), pitch 2*CC
{
  const int b  = blockIdx.x >> 5;
  const int c0 = (blockIdx.x & 31) * WKV_CPB;
  const int tid = threadIdx.x;
  const int cl = tid & 31;
  const int j  = tid >> 5;
  const int c  = c0 + cl;

  const float w   = -__expf(decay[c]);
  const float lam = __expf(w);
  const float eu  = __expf(first[c]);

  const size_t base  = (size_t)b * TT * CC + (size_t)j * WKV_L * CC + c;
  size_t obase = ((size_t)b * TT + (size_t)j * WKV_L) * (2 * CC) + c;

  // phase 1: local scan (state only)
  float a = 0.f, bb = 0.f;
  size_t idx = base;
  for (int i = 0; i < WKV_L; ++i, idx += CC) {
    const float kt = bf2f(k[idx]), vt = bf2f(v[idx]);
    const float ek = __expf(kt);
    a  = fmaf(lam, a, ek * vt);
    bb = fmaf(lam, bb, ek);
  }

  // phase 2: exclusive carry scan over chunks
  __shared__ float sA[WKV_NCH][WKV_CPB];
  __shared__ float sB[WKV_NCH][WKV_CPB];
  sA[j][cl] = a; sB[j][cl] = bb;
  __syncthreads();
  if (tid < WKV_CPB) {
    float ca = 0.f, cb = 0.f;
    const float cw   = -__expf(decay[c0 + tid]);
    const float cLam = __expf(cw * (float)WKV_L);
#pragma unroll
    for (int q = 0; q < WKV_NCH; ++q) {
      const float ta = sA[q][tid], tb = sB[q][tid];
      sA[q][tid] = ca; sB[q][tid] = cb;
      ca = fmaf(cLam, ca, ta);
      cb = fmaf(cLam, cb, tb);
    }
  }
  __syncthreads();
  a = sA[j][cl]; bb = sB[j][cl];

  // phase 3: replay with carry-in, emit sigmoid(r)*y into A' rwkv half
  idx = base;
  for (int i = 0; i < WKV_L; ++i, idx += CC, obase += 2 * CC) {
    const float kt = bf2f(k[idx]), vt = bf2f(v[idx]), rt = bf2f(r[idx]);
    const float ek = __expf(kt);
    const float e2 = eu * ek;
    const float y  = (a + e2 * vt) / (bb + e2);
    out[obase] = f2bf(sigm(rt) * y);
    a  = fmaf(lam, a, ek * vt);
    bb = fmaf(lam, bb, ek);
  }
}

// ---------------------------------------------------------------------------
// Weight f32 -> bf16 conversion. Segments 3 (Wo) and 4 (Wsh) are interleaved
// into W' = [Wsh | Wo] rows of pitch 2048 for the merged short+Wo GEMM.
// ---------------------------------------------------------------------------
struct ConvArgs { const float* src[8]; int end[8]; int dstoff[8]; };

__global__ __launch_bounds__(256) void conv_w(ConvArgs args, u16* __restrict__ dst)
{
  const int i = (blockIdx.x * 256 + threadIdx.x) * 4;
  int seg = 0;
  const float* sp = args.src[0];
  int base = 0;
#pragma unroll
  for (int s = 1; s < 8; ++s) {
    if (i >= args.end[s - 1]) { seg = s; sp = args.src[s]; base = args.end[s - 1]; }
  }
  const int l = i - base;
  const float4 vv = *(const float4*)(sp + l);
  int dsti;
  if (seg == 3)      { int row = l >> 10, col = l & 1023; dsti = args.dstoff[3] + row * 2048 + 1024 + col; }
  else if (seg == 4) { int row = l >> 10, col = l & 1023; dsti = args.dstoff[4] + row * 2048 + col; }
  else               dsti = args.dstoff[seg] + l;
  ushort4 d;
  d.x = f2bf(vv.x); d.y = f2bf(vv.y); d.z = f2bf(vv.z); d.w = f2bf(vv.w);
  *(ushort4*)(dst + dsti) = d;
}

extern "C" void kernel_launch(void* const* d_in, const int* in_sizes, int n_in,
                              void* d_out, int out_size, void* d_ws, size_t ws_size,
                              hipStream_t stream)
{
  const float* x    = (const float*)d_in[0];
  const float* ln1w = (const float*)d_in[1];
  const float* ln1b = (const float*)d_in[2];
  const float* ln2w = (const float*)d_in[3];
  const float* ln2b = (const float*)d_in[4];
  const float* tdec = (const float*)d_in[5];
  const float* tfir = (const float*)d_in[6];
  const float* amk  = (const float*)d_in[7];
  const float* amv  = (const float*)d_in[8];
  const float* amr  = (const float*)d_in[9];
  const float* Wk   = (const float*)d_in[10];
  const float* Wv   = (const float*)d_in[11];
  const float* Wr   = (const float*)d_in[12];
  const float* Wo   = (const float*)d_in[13];
  const float* fmk  = (const float*)d_in[14];
  const float* fmr  = (const float*)d_in[15];
  const float* WfK  = (const float*)d_in[16];
  const float* WfR  = (const float*)d_in[17];
  const float* WfV  = (const float*)d_in[18];
  const float* Wsh  = (const float*)d_in[19];
  float* out = (float*)d_out;
  char* ws = (char*)d_ws;

  // workspace: 28 MB bf16 weights + six 32 MB regions = 230,686,720 B total.
  u16* wW = (u16*)(ws);
  u16* U0 = (u16*)(ws + 29360128);
  u16* U1 = (u16*)(ws + 62914560);
  u16* U2 = (u16*)(ws + 96468992);
  u16* U3 = (u16*)(ws + 130023424);
  u16* U4 = (u16*)(ws + 163577856);   // A' = U4+U5, 64 MB contiguous

  // liveness-based aliases:
  u16* xk   = U0;          // prep1
  u16* xv   = U1;
  u16* xr   = U2;
  u16* Ap   = U4;          // A' [M, 2C]: cols 0..C-1 = bf16(x), C..2C-1 = rwkv
  u16* kbuf = U3;          // k = xk*Wk   (U0 dead after)
  u16* vbuf = U0;          // v = xv*Wv   (U1 dead after)
  u16* rbuf = U1;          // r = xr*Wr   (U2 dead after)
  u16* gk   = U0;          // prep2       (U0 dead after wkv)
  u16* gr   = U1;
  u16* kkb  = U2;          // kk [M,F] bf16 = 128 MB, spans U2..U5 (all dead)
  u16* rffn = U0;          // r_ffn       (gk/U0 dead after kk GEMM)

  u16* bWk   = wW + 0;
  u16* bWv   = wW + 1048576;
  u16* bWr   = wW + 2097152;
  u16* bWsWo = wW + 3145728;   // W' [C, 2C] interleaved [Wsh | Wo]
  u16* bWfR  = wW + 5242880;
  u16* bWfK  = wW + 6291456;
  u16* bWfV  = wW + 10485760;

  ConvArgs ca;
  ca.src[0] = Wk;  ca.src[1] = Wv;  ca.src[2] = Wr;  ca.src[3] = Wo;
  ca.src[4] = Wsh; ca.src[5] = WfR; ca.src[6] = WfK; ca.src[7] = WfV;
  const int e = 1048576;
  ca.end[0] = e;     ca.end[1] = 2*e;  ca.end[2] = 3*e;  ca.end[3] = 4*e;
  ca.end[4] = 5*e;   ca.end[5] = 6*e;  ca.end[6] = 10*e; ca.end[7] = 14*e;
  ca.dstoff[0] = 0;     ca.dstoff[1] = e;    ca.dstoff[2] = 2*e;
  ca.dstoff[3] = 3*e;   ca.dstoff[4] = 3*e;  // both into W' (interleaved)
  ca.dstoff[5] = 5*e;   ca.dstoff[6] = 6*e;  ca.dstoff[7] = 10*e;

  conv_w<<<14336, 256, 0, stream>>>(ca, wW);
  prep_mix<<<MM, 256, 0, stream>>>(x, ln1w, ln1b, amk, amv, amr, xk, xv, xr, Ap);

  dim3 g8(MM / 256, CC / 256);
  gemm_bt<3><<<g8, 512, 0, stream>>>(xk, bWk, nullptr, kbuf, nullptr, CC, CC);
  gemm_bt<3><<<g8, 512, 0, stream>>>(xv, bWv, nullptr, vbuf, nullptr, CC, CC);
  gemm_bt<3><<<g8, 512, 0, stream>>>(xr, bWr, nullptr, rbuf, nullptr, CC, CC);

  wkv_scan<<<BB * (CC / WKV_CPB), 1024, 0, stream>>>(kbuf, vbuf, rbuf, tdec, tfir, Ap + CC);

  // out = [xb | rwkv] * [Wsh | Wo]^T   (single K=2048 GEMM)
  gemm_bt<0><<<g8, 512, 0, stream>>>(Ap, bWsWo, out, nullptr, nullptr, CC, 2 * CC);

  prep_mix<<<MM, 256, 0, stream>>>(out, ln2w, ln2b, fmk, nullptr, fmr, gk, nullptr, gr, nullptr);

  dim3 gF(MM / 256, FF / 256);
  gemm_bt<2><<<gF, 512, 0, stream>>>(gk, bWfK, nullptr, kkb, nullptr, FF, CC);  // kk = relu(gk*WfK)^2
  gemm_bt<3><<<g8, 512, 0, stream>>>(gr, bWfR, nullptr, rffn, nullptr, CC, CC);
  // out += sigm(rffn) * (kk * WfV)   (fused final_add)
  gemm_bt<4><<<g8, 512, 0, stream>>>(kkb, bWfV, out, nullptr, rffn, CC, FF);
}